// Round 9
// baseline (288.674 us; speedup 1.0000x reference)
//
#include <hip/hip_runtime.h>

// J-loss via MFMA: T[b,i,k] = sum_p pred[b,i,p] * onehot(target[b,p]==k)
// j[b] = -sum_{i!=k} log(0.5 + 0.5*(T[b,i,i]/n[b,i] - T[b,i,k]/n[b,k]))
//
// R8 post-mortem: nontemporal = -4.5us (kept). Kernel ~60us = 2.5 TB/s,
// matching an outstanding-miss x latency bound (192 wave-loads/CU).
// R9: ONE lever — per-wave MLP 12 -> 24 in-flight loads (manual 4-step
// load-then-compute pipeline). Counts-MFMA dropped to free VGPRs (counts via
// ballot kernel); no occupancy cap (expect ~140 VGPR, 3 waves/SIMD).

#define BB 8
#define CC 32
#define HW 147456                 // 384*384
#define CHUNK_PX 1024             // pixels per block (4 waves x 256 px)
#define NCHUNK (HW / CHUNK_PX)    // 144
#define CNT_PX 4096
#define NCNT (HW / CNT_PX)        // 36

typedef __attribute__((ext_vector_type(8))) short short8;
typedef __attribute__((ext_vector_type(4))) float float4v;
typedef __attribute__((ext_vector_type(4))) unsigned uint4v;
typedef __attribute__((ext_vector_type(4))) int int4v;

__device__ __forceinline__ unsigned pk(float lo, float hi) {
    return __builtin_amdgcn_perm(__float_as_uint(hi), __float_as_uint(lo), 0x07060302u);
}
__device__ __forceinline__ unsigned oh2(int ta, int tb, int m) {
    return (ta == m ? 0x3F80u : 0u) | (tb == m ? 0x3F800000u : 0u);
}

__global__ __launch_bounds__(256) void jloss_mfma(
    const float* __restrict__ pred,    // [B][C][HW]
    const int*   __restrict__ target,  // [B][HW]
    float*       __restrict__ T)       // [B][C][C] pre-zeroed
{
    const int tid  = threadIdx.x;
    const int w    = tid >> 6;
    const int l    = tid & 63;
    const int quad = l >> 4;
    const int m    = l & 15;
    const int blk  = blockIdx.x;
    const int b    = blk / NCHUNK;
    const int chunk= blk % NCHUNK;

    const long pb_wave = (long)chunk * CHUNK_PX + w * 256;
    const float* predb = pred + (long)b * CC * HW;
    const int*   tgtb  = target + (long)b * HW;

    const float* p0 = predb + (long)m * HW + pb_wave + quad * 8;  // channel m
    const float* p1 = p0 + (long)16 * HW;                         // channel m+16
    const int*   tp = tgtb + pb_wave + quad * 8;

    float4v acc00 = {0,0,0,0}, acc01 = {0,0,0,0};
    float4v acc10 = {0,0,0,0}, acc11 = {0,0,0,0};

    #pragma unroll 1
    for (int g = 0; g < 2; ++g) {      // 2 groups x 4 K-steps
        float4v A[4][4];               // [step][a0l,a0h,a1l,a1h] = 64 VGPR
        int4v   Tt[4][2];              // [step][t0,t1]           = 32 VGPR

        #pragma unroll
        for (int s = 0; s < 4; ++s) {  // issue ALL 24 loads first (MLP)
            const int o = (g * 4 + s) * 32;
            A[s][0] = __builtin_nontemporal_load((const float4v*)(p0 + o));
            A[s][1] = __builtin_nontemporal_load((const float4v*)(p0 + o + 4));
            A[s][2] = __builtin_nontemporal_load((const float4v*)(p1 + o));
            A[s][3] = __builtin_nontemporal_load((const float4v*)(p1 + o + 4));
            Tt[s][0] = __builtin_nontemporal_load((const int4v*)(tp + o));
            Tt[s][1] = __builtin_nontemporal_load((const int4v*)(tp + o + 4));
        }

        #pragma unroll
        for (int s = 0; s < 4; ++s) {
            const float4v a0l = A[s][0], a0h = A[s][1], a1l = A[s][2], a1h = A[s][3];
            const int4v t0 = Tt[s][0], t1 = Tt[s][1];
            union { short8 sv; uint4v u; } A0, A1, B0, B1;
            A0.u[0] = pk(a0l[0], a0l[1]); A0.u[1] = pk(a0l[2], a0l[3]);
            A0.u[2] = pk(a0h[0], a0h[1]); A0.u[3] = pk(a0h[2], a0h[3]);
            A1.u[0] = pk(a1l[0], a1l[1]); A1.u[1] = pk(a1l[2], a1l[3]);
            A1.u[2] = pk(a1h[0], a1h[1]); A1.u[3] = pk(a1h[2], a1h[3]);
            B0.u[0] = oh2(t0[0], t0[1], m);   B0.u[1] = oh2(t0[2], t0[3], m);
            B0.u[2] = oh2(t1[0], t1[1], m);   B0.u[3] = oh2(t1[2], t1[3], m);
            const int m16 = m + 16;
            B1.u[0] = oh2(t0[0], t0[1], m16); B1.u[1] = oh2(t0[2], t0[3], m16);
            B1.u[2] = oh2(t1[0], t1[1], m16); B1.u[3] = oh2(t1[2], t1[3], m16);

            acc00 = __builtin_amdgcn_mfma_f32_16x16x32_bf16(A0.sv, B0.sv, acc00, 0, 0, 0);
            acc01 = __builtin_amdgcn_mfma_f32_16x16x32_bf16(A0.sv, B1.sv, acc01, 0, 0, 0);
            acc10 = __builtin_amdgcn_mfma_f32_16x16x32_bf16(A1.sv, B0.sv, acc10, 0, 0, 0);
            acc11 = __builtin_amdgcn_mfma_f32_16x16x32_bf16(A1.sv, B1.sv, acc11, 0, 0, 0);
        }
    }

    // cross-wave reduce in LDS, then one global atomic per entry
    __shared__ float red[4][CC][CC];   // 16 KB
    #pragma unroll
    for (int r = 0; r < 4; ++r) {      // C layout: row=quad*4+r, col=m (m89-verified)
        red[w][quad*4 + r     ][m     ] = acc00[r];
        red[w][quad*4 + r     ][m + 16] = acc01[r];
        red[w][quad*4 + r + 16][m     ] = acc10[r];
        red[w][quad*4 + r + 16][m + 16] = acc11[r];
    }
    __syncthreads();

    float* Tb = T + (long)b * CC * CC;
    const float* rp = &red[0][0][0];
    for (int j = tid; j < CC * CC; j += 256) {
        const float s = rp[j] + rp[1024 + j] + rp[2048 + j] + rp[3072 + j];
        atomicAdd(&Tb[j], s);
    }
}

__global__ __launch_bounds__(256) void jloss_cnt(
    const int* __restrict__ target,    // [B][HW]
    float*     __restrict__ cnt)       // [B][C] pre-zeroed
{
    const int tid = threadIdx.x;
    const int l   = tid & 63;
    const int blk = blockIdx.x;
    const int b   = blk / NCNT;
    const int seg = blk % NCNT;
    const int* tb = target + (long)b * HW + (long)seg * CNT_PX + tid * 4;

    int c[CC];
    #pragma unroll
    for (int k = 0; k < CC; ++k) c[k] = 0;
    #pragma unroll
    for (int it = 0; it < CNT_PX / (256 * 4); ++it) {   // 4 iters x int4
        const int4 t = *(const int4*)(tb + it * 1024);
        #pragma unroll
        for (int k = 0; k < CC; ++k)
            c[k] += (int)__popcll(__ballot(t.x == k)) + (int)__popcll(__ballot(t.y == k))
                  + (int)__popcll(__ballot(t.z == k)) + (int)__popcll(__ballot(t.w == k));
    }
    if (l == 0) {
        #pragma unroll
        for (int k = 0; k < CC; ++k)
            atomicAdd(&cnt[b * CC + k], (float)c[k]);
    }
}

__global__ __launch_bounds__(256) void jloss_final(
    const float* __restrict__ T,
    const float* __restrict__ cnt,
    float*       __restrict__ out)
{
    const int b   = blockIdx.x;
    const int tid = threadIdx.x;
    __shared__ float diag_s[CC];
    __shared__ float inv_n[CC];
    __shared__ float wsum[4];

    const float* Tb = T + (long)b * CC * CC;
    const float* cb = cnt + b * CC;

    if (tid < CC) {
        const float inv = 1.0f / cb[tid];
        inv_n[tid]  = inv;
        diag_s[tid] = Tb[tid * CC + tid] * inv;
    }
    __syncthreads();

    float sum = 0.0f;
    for (int idx = tid; idx < CC * CC; idx += 256) {
        const int i = idx >> 5;
        const int k = idx & 31;
        if (i != k) {
            const float S = Tb[idx] * inv_n[k];
            sum += logf(0.5f + 0.5f * (diag_s[i] - S));
        }
    }
    #pragma unroll
    for (int off = 32; off > 0; off >>= 1) sum += __shfl_down(sum, off, 64);
    if ((tid & 63) == 0) wsum[tid >> 6] = sum;
    __syncthreads();
    if (tid == 0) out[b] = -(wsum[0] + wsum[1] + wsum[2] + wsum[3]);
}

extern "C" void kernel_launch(void* const* d_in, const int* in_sizes, int n_in,
                              void* d_out, int out_size, void* d_ws, size_t ws_size,
                              hipStream_t stream) {
    const float* pred   = (const float*)d_in[0];
    const int*   target = (const int*)d_in[1];
    float* out = (float*)d_out;

    float* T   = (float*)d_ws;                       // 8*32*32 floats
    float* cnt = (float*)d_ws + BB * CC * CC;        // 8*32 floats

    hipMemsetAsync(d_ws, 0, (BB * CC * CC + BB * CC) * sizeof(float), stream);

    jloss_cnt  <<<BB * NCNT,   256, 0, stream>>>(target, cnt);
    jloss_mfma <<<BB * NCHUNK, 256, 0, stream>>>(pred, target, T);
    jloss_final<<<BB, 256, 0, stream>>>(T, cnt, out);
}